// Round 10
// baseline (2141.204 us; speedup 1.0000x reference)
//
#include <hip/hip_runtime.h>
#include <cstdio>
#include <cstdint>

// ---------------------------------------------------------------------------
// Transformer-XL relative MHA, MI355X/gfx950.  B=16 T=512 D=512 H=8 hd=64.
// Round 10: software-pipelined prefetch everywhere. GEMM core double-buffers
// fragment loads (chunk k+1 in flight during chunk k MFMAs) — R9 showed the
// barrier-free loop was a raw latency chain (MfmaUtil 14% == 77cyc/500cyc).
// Flash double-buffers all k/p/v fragments per t-step. megaprep stores
// vectorized to 16B (LN: 4 rows/block, lane owns 8 contiguous cols).
// pack(r,k) = (r>>4)*8192 + (k>>5)*512 + ((k>>3)&3)*128 + (r&15)*8 + (k&7)
// Precision: plain bf16 everywhere (absmax pinned by logit path at 0.0078).
// ---------------------------------------------------------------------------

typedef short s16x8 __attribute__((ext_vector_type(8)));
typedef float f32x4 __attribute__((ext_vector_type(4)));
typedef unsigned short u16x4 __attribute__((ext_vector_type(4)));
typedef unsigned short u16x8 __attribute__((ext_vector_type(8)));

#define CSCALE 0.1803368801111204f  // log2(e)/8

#if __has_builtin(__builtin_amdgcn_exp2f)
#define EXP2(x) __builtin_amdgcn_exp2f(x)
#else
#define EXP2(x) exp2f(x)
#endif

__device__ __forceinline__ unsigned short f2bf(float f) {  // RNE
  unsigned int u = __builtin_bit_cast(unsigned int, f);
  unsigned int r = (u + 0x7FFFu + ((u >> 16) & 1u)) >> 16;
  return (unsigned short)r;
}
__device__ __forceinline__ float bf2f(unsigned short h) {
  unsigned int u = ((unsigned int)h) << 16;
  return __builtin_bit_cast(float, u);
}
// fragment-strip packing: strips of 16 rows x 512 k (8192 shorts)
__device__ __forceinline__ size_t pk(int row, int col) {
  return (size_t)(row >> 4) * 8192 + (col >> 5) * 512 + ((col >> 3) & 3) * 128 +
         (row & 15) * 8 + (col & 7);
}

// ---------------- fused prep (vectorized stores) ---------------------------
// [0,2048): LN 4 rows/block (wave per row, lane owns 8 cols)
// [2048,6144): pe -> per-b packed strips, 8 elems/thread
// [6144,6784): weights -> packed, 8 elems/thread
__global__ __launch_bounds__(256) void megaprep(
    const float* __restrict__ x, const float* __restrict__ g,
    const float* __restrict__ bb, unsigned short* __restrict__ xpk,
    const float* __restrict__ pe, unsigned short* __restrict__ pepk,
    const float* __restrict__ Wq, const float* __restrict__ Wk,
    const float* __restrict__ Wp, const float* __restrict__ Wv,
    const float* __restrict__ Wo, const float* __restrict__ bq,
    const float* __restrict__ bk, unsigned short* __restrict__ wqk,
    unsigned short* __restrict__ wpm, unsigned short* __restrict__ wvm,
    unsigned short* __restrict__ wom, float* __restrict__ bqk) {
  const int bid = blockIdx.x, tid = threadIdx.x;
  if (bid < 2048) {  // LN: row = bid*4 + wave
    const int wave = tid >> 6, lane = tid & 63;
    const int row = bid * 4 + wave;
    const int c0 = lane * 8;
    const float* xr = x + (size_t)row * 512 + c0;
    float4 v0 = *(const float4*)xr;
    float4 v1 = *(const float4*)(xr + 4);
    float vv[8] = {v0.x, v0.y, v0.z, v0.w, v1.x, v1.y, v1.z, v1.w};
    float s = 0.f, ss = 0.f;
#pragma unroll
    for (int j = 0; j < 8; ++j) { s += vv[j]; ss += vv[j] * vv[j]; }
#pragma unroll
    for (int d = 1; d < 64; d <<= 1) {
      s += __shfl_xor(s, d, 64);
      ss += __shfl_xor(ss, d, 64);
    }
    const float mu = s * (1.0f / 512.0f);
    const float var = ss * (1.0f / 512.0f) - mu * mu;
    const float rstd = rsqrtf(var + 1e-5f);
    u16x8 o;
#pragma unroll
    for (int j = 0; j < 8; ++j)
      o[j] = f2bf((vv[j] - mu) * rstd * g[c0 + j] + bb[c0 + j]);
    *(u16x8*)(xpk + pk(row, c0)) = o;
  } else if (bid < 6144) {  // pe: 8 elems/thread
    int gid = (bid - 2048) * 256 + tid;
    int e = gid * 8;  // over 16384*512
    int r = e >> 9, c = e & 511;
    int b = r >> 10, u = r & 1023;
    u16x8 o = {0, 0, 0, 0, 0, 0, 0, 0};
    if (u < 1023) {
      const float* src = pe + (size_t)(b * 1023 + u) * 512 + c;
      float4 v0 = *(const float4*)src;
      float4 v1 = *(const float4*)(src + 4);
      o[0] = f2bf(v0.x); o[1] = f2bf(v0.y); o[2] = f2bf(v0.z); o[3] = f2bf(v0.w);
      o[4] = f2bf(v1.x); o[5] = f2bf(v1.y); o[6] = f2bf(v1.z); o[7] = f2bf(v1.w);
    }
    *(u16x8*)(pepk + (size_t)b * 524288 + pk(u, c)) = o;
  } else {  // weights: 8 elems/thread
    int gid = (bid - 6144) * 256 + tid;
    int idx = gid * 8;  // over 5*262144
    int region = idx >> 18, off = idx & 262143;
    const float* src = (region == 0)   ? Wq
                       : (region == 1) ? Wk
                       : (region == 2) ? Wp
                       : (region == 3) ? Wv
                                       : Wo;
    float4 v0 = *(const float4*)(src + off);
    float4 v1 = *(const float4*)(src + off + 4);
    u16x8 o;
    o[0] = f2bf(v0.x); o[1] = f2bf(v0.y); o[2] = f2bf(v0.z); o[3] = f2bf(v0.w);
    o[4] = f2bf(v1.x); o[5] = f2bf(v1.y); o[6] = f2bf(v1.z); o[7] = f2bf(v1.w);
    int n = off >> 9, k = off & 511;
    unsigned short* dst;
    int nrow = n;
    if (region == 0) { dst = wqk; }
    else if (region == 1) { dst = wqk; nrow = n + 512; }
    else if (region == 2) { dst = wpm; }
    else if (region == 3) { dst = wvm; }
    else { dst = wom; }
    *(u16x8*)(dst + pk(nrow, k)) = o;
    if (idx < 1024) {
#pragma unroll
      for (int j = 0; j < 8; j++) {
        int ii = idx + j;
        bqk[ii] = (ii < 512) ? bq[ii] : bk[ii - 512];
      }
    }
  }
}

// ---------------- direct-load 64x64 GEMM core, prefetched ------------------
// Double-buffered fragments: chunk kc+1 loads issue before chunk kc MFMAs.
__device__ __forceinline__ void gemm64_direct(
    const unsigned short* __restrict__ Apk, const unsigned short* __restrict__ Bpk,
    int mstrip0, int nstrip0, int lane, f32x4 acc[4][4]) {
  const unsigned short* ab = Apk + (size_t)mstrip0 * 8192 + lane * 8;
  const unsigned short* bb = Bpk + (size_t)nstrip0 * 8192 + lane * 8;
  s16x8 af[2][4], bf[2][4];
#pragma unroll
  for (int mt = 0; mt < 4; ++mt) af[0][mt] = *(const s16x8*)(ab + mt * 8192);
#pragma unroll
  for (int nt = 0; nt < 4; ++nt) bf[0][nt] = *(const s16x8*)(bb + nt * 8192);
#pragma unroll
  for (int kc = 0; kc < 16; ++kc) {
    const int cur = kc & 1, nxt = cur ^ 1;
    if (kc < 15) {
#pragma unroll
      for (int mt = 0; mt < 4; ++mt)
        af[nxt][mt] = *(const s16x8*)(ab + (size_t)mt * 8192 + (kc + 1) * 512);
#pragma unroll
      for (int nt = 0; nt < 4; ++nt)
        bf[nxt][nt] = *(const s16x8*)(bb + (size_t)nt * 8192 + (kc + 1) * 512);
    }
#pragma unroll
    for (int mt = 0; mt < 4; ++mt)
#pragma unroll
      for (int nt = 0; nt < 4; ++nt)
        acc[mt][nt] = __builtin_amdgcn_mfma_f32_16x16x32_bf16(
            af[cur][mt], bf[cur][nt], acc[mt][nt], 0, 0, 0);
  }
}

// merged projections: wave-tiles — qk [0,2048), p [2048,4096), v [4096,5120)
__global__ __launch_bounds__(256) void proj_all(
    const unsigned short* __restrict__ xpk, const unsigned short* __restrict__ pepk,
    const unsigned short* __restrict__ wqk, const unsigned short* __restrict__ wpm,
    const unsigned short* __restrict__ wvm, const float* __restrict__ bqk,
    const float* __restrict__ bp, const float* __restrict__ bv,
    const float* __restrict__ cbv, const float* __restrict__ pbv,
    unsigned short* __restrict__ qc, unsigned short* __restrict__ qp,
    unsigned short* __restrict__ kb, unsigned short* __restrict__ pbuf,
    unsigned short* __restrict__ vth) {
  const int tid = threadIdx.x, lane = tid & 63, wave = tid >> 6;
  const int w = blockIdx.x * 4 + wave;
  const int fr = lane & 15, hi2 = lane >> 4;
  f32x4 fz = {0.f, 0.f, 0.f, 0.f};
  f32x4 acc[4][4];
#pragma unroll
  for (int i = 0; i < 4; i++)
#pragma unroll
    for (int j = 0; j < 4; j++) acc[i][j] = fz;

  if (w < 2048) {  // qk: 128 m-tiles x 16 n-tiles
    int m_t = w >> 4, n_t = w & 15;
    gemm64_direct(xpk, wqk, m_t * 4, n_t * 4, lane, acc);
    int m0 = m_t * 64, n0 = n_t * 64;
#pragma unroll
    for (int nt = 0; nt < 4; ++nt) {
      int col = n0 + nt * 16 + fr;
      float bval = bqk[col];
#pragma unroll
      for (int mt = 0; mt < 4; ++mt) {
        int row = m0 + mt * 16 + hi2 * 4;
        int b = row >> 9, s15 = row & 15, s16i = (row & 511) >> 4;
        if (col < 512) {
          int h = col >> 6, cc = col & 63;
          size_t idx = ((size_t)(b * 8 + h) * 32 + s16i) * 1024 +
                       (cc >> 5) * 512 + ((cc & 31) >> 3) * 128 + (cc & 7);
          float cbc = cbv[col], pbc = pbv[col];
#pragma unroll
          for (int r = 0; r < 4; ++r) {
            float val = acc[mt][nt][r] + bval;
            qc[idx + (s15 + r) * 8] = f2bf((val + cbc) * CSCALE);
            qp[idx + (s15 + r) * 8] = f2bf((val + pbc) * CSCALE);
          }
        } else {
          int c2 = col - 512, h = c2 >> 6, cc = c2 & 63;
          size_t idx = ((size_t)(b * 8 + h) * 32 + s16i) * 1024 +
                       (cc >> 5) * 512 + ((cc & 31) >> 3) * 128 + (cc & 7);
#pragma unroll
          for (int r = 0; r < 4; ++r)
            kb[idx + (s15 + r) * 8] = f2bf(acc[mt][nt][r] + bval);
        }
      }
    }
  } else if (w < 4096) {  // p: 256 m-tiles x 8 n-tiles (per-b packed A)
    int w2 = w - 2048;
    int m_t = w2 >> 3, n_t = w2 & 7;
    int bb_ = m_t >> 4;
    gemm64_direct(pepk + (size_t)bb_ * 524288, wpm, (m_t & 15) * 4, n_t * 4,
                  lane, acc);
    int m0e = m_t * 64, n0 = n_t * 64;
    int b = m0e >> 10, u0 = m0e & 1023;
#pragma unroll
    for (int nt = 0; nt < 4; ++nt) {
      int col = n0 + nt * 16 + fr;
      float bval = bp[col];
      int h = col >> 6, cc = col & 63;
      size_t cbase = (size_t)(b * 8 + h) * 64 * 1024 + (cc >> 5) * 512 +
                     ((cc & 31) >> 3) * 128 + (cc & 7);
#pragma unroll
      for (int mt = 0; mt < 4; ++mt) {
        int ub = u0 + mt * 16 + hi2 * 4;
#pragma unroll
        for (int r = 0; r < 4; ++r) {
          int u = ub + r;
          float val = (u >= 1023) ? 0.f : (acc[mt][nt][r] + bval);
          pbuf[cbase + (size_t)(u >> 4) * 1024 + (u & 15) * 8] = f2bf(val);
        }
      }
    }
  } else {  // v: 128 m-tiles x 8 n-tiles -> vT packed
    int w3 = w - 4096;
    int m_t = w3 >> 3, n_t = w3 & 7;
    gemm64_direct(xpk, wvm, m_t * 4, n_t * 4, lane, acc);
    int m0 = m_t * 64, n0 = n_t * 64;
#pragma unroll
    for (int nt = 0; nt < 4; ++nt) {
      int col = n0 + nt * 16 + fr;
      float bval = bv[col];
      int h = col >> 6, d = col & 63;
#pragma unroll
      for (int mt = 0; mt < 4; ++mt) {
        int rowb = m0 + mt * 16 + hi2 * 4;
        int b = rowb >> 9, t = rowb & 511;
        size_t idx = ((size_t)((b * 8 + h) * 4 + (d >> 4)) * 16 + (t >> 5)) * 512 +
                     ((t & 31) >> 3) * 128 + (d & 15) * 8 + (t & 7);
        u16x4 hv;
#pragma unroll
        for (int r = 0; r < 4; ++r) hv[r] = f2bf(acc[mt][nt][r] + bval);
        *(u16x4*)(vth + idx) = hv;
      }
    }
  }
}

__global__ __launch_bounds__(256) void out_gemm(
    const unsigned short* __restrict__ ctxpk, const unsigned short* __restrict__ wom,
    const float* __restrict__ bo, float* __restrict__ out) {
  const int tid = threadIdx.x, lane = tid & 63, wave = tid >> 6;
  const int w = blockIdx.x * 4 + wave;  // 1024 waves: 128 m x 8 n
  const int fr = lane & 15, hi2 = lane >> 4;
  int m_t = w >> 3, n_t = w & 7;
  f32x4 fz = {0.f, 0.f, 0.f, 0.f};
  f32x4 acc[4][4];
#pragma unroll
  for (int i = 0; i < 4; i++)
#pragma unroll
    for (int j = 0; j < 4; j++) acc[i][j] = fz;
  gemm64_direct(ctxpk, wom, m_t * 4, n_t * 4, lane, acc);
  int m0 = m_t * 64, n0 = n_t * 64;
#pragma unroll
  for (int nt = 0; nt < 4; ++nt) {
    int col = n0 + nt * 16 + fr;
    float bval = bo[col];
#pragma unroll
    for (int mt = 0; mt < 4; ++mt) {
      int row = m0 + mt * 16 + hi2 * 4;
#pragma unroll
      for (int r = 0; r < 4; ++r)
        out[(size_t)(row + r) * 512 + col] = acc[mt][nt][r] + bval;
    }
  }
}

// ---------------- barrier-free flash attention, prefetched steps -----------
// grid 1024; id%128=(b,h). Wave owns 16 q-rows. Fixed-max softmax. All k/p/v
// fragments double-buffered: step+1 loads issue before step's compute.
__global__ __launch_bounds__(256) void flash_attn(
    const unsigned short* __restrict__ qc, const unsigned short* __restrict__ qp,
    const unsigned short* __restrict__ kb, const unsigned short* __restrict__ pm,
    const unsigned short* __restrict__ vth, unsigned short* __restrict__ ctxpk) {
  const int id = blockIdx.x;
  const int bh = id & 127, b = bh >> 3, h = bh & 7;
  const int s_blk = id >> 7;
  const int tid = threadIdx.x, wave = tid >> 6, lane = tid & 63;
  const int fr = lane & 15, hi2 = lane >> 4, fc = hi2 * 8;
  const int s0w = s_blk * 64 + wave * 16;
  const int crow = hi2 * 4;

  __shared__ __align__(16) unsigned short Ph_s[4][16][40];
  unsigned short(*Phw)[40] = Ph_s[wave];

  int srcl[4];
#pragma unroll
  for (int r = 0; r < 4; ++r) srcl[r] = (hi2 << 4) | ((fr - (crow + r) - 1) & 15);

  const size_t qtb = ((size_t)(b * 8 + h) * 32 + (s0w >> 4)) * 1024 + lane * 8;
  s16x8 aqc0 = *(const s16x8*)(qc + qtb);
  s16x8 aqc1 = *(const s16x8*)(qc + qtb + 512);
  s16x8 aqp0 = *(const s16x8*)(qp + qtb);
  s16x8 aqp1 = *(const s16x8*)(qp + qtb + 512);

  const unsigned short* kpk = kb + (size_t)(b * 8 + h) * 32 * 1024 + lane * 8;
  const unsigned short* ppk = pm + (size_t)(b * 8 + h) * 64 * 1024 + lane * 8;
  const unsigned short* vhk = vth + (size_t)(b * 8 + h) * 64 * 512 + lane * 8;

  f32x4 fz = {0.f, 0.f, 0.f, 0.f};
  f32x4 Oacc[4] = {fz, fz, fz, fz};
  float lsum[4] = {0.f, 0.f, 0.f, 0.f};

  s16x8 kf[2][4], pf[2][6], vf[2][4];
  auto load_step = [&](int step, int buf) {
    const int t0 = step * 32;
    const int u0w = t0 - s0w + 496;
    const int kt = t0 >> 4, ut = u0w >> 4, vt = t0 >> 5;
#pragma unroll
    for (int nt = 0; nt < 2; ++nt) {
      const unsigned short* kr = kpk + (size_t)(kt + nt) * 1024;
      kf[buf][2 * nt] = *(const s16x8*)kr;
      kf[buf][2 * nt + 1] = *(const s16x8*)(kr + 512);
    }
#pragma unroll
    for (int nt = 0; nt < 3; ++nt) {
      const unsigned short* pr = ppk + (size_t)(ut + nt) * 1024;
      pf[buf][2 * nt] = *(const s16x8*)pr;
      pf[buf][2 * nt + 1] = *(const s16x8*)(pr + 512);
    }
#pragma unroll
    for (int nt = 0; nt < 4; ++nt)
      vf[buf][nt] = *(const s16x8*)(vhk + (size_t)(nt * 16 + vt) * 512);
  };

  load_step(0, 0);
  for (int step = 0; step < 16; ++step) {
    const int cur = step & 1;
    if (step < 15) load_step(step + 1, cur ^ 1);
    // content scores
    f32x4 sc[2] = {fz, fz};
#pragma unroll
    for (int nt = 0; nt < 2; ++nt) {
      sc[nt] = __builtin_amdgcn_mfma_f32_16x16x32_bf16(aqc0, kf[cur][2 * nt],
                                                       sc[nt], 0, 0, 0);
      sc[nt] = __builtin_amdgcn_mfma_f32_16x16x32_bf16(aqc1, kf[cur][2 * nt + 1],
                                                       sc[nt], 0, 0, 0);
    }
    // pos scores over 48-wide window
    f32x4 sp[3];
#pragma unroll
    for (int nt = 0; nt < 3; ++nt) {
      f32x4 t = fz;
      t = __builtin_amdgcn_mfma_f32_16x16x32_bf16(aqp0, pf[cur][2 * nt], t, 0, 0, 0);
      t = __builtin_amdgcn_mfma_f32_16x16x32_bf16(aqp1, pf[cur][2 * nt + 1], t, 0, 0, 0);
      sp[nt] = t;
    }
    float sj[3][4];
#pragma unroll
    for (int j = 0; j < 3; ++j)
#pragma unroll
      for (int r = 0; r < 4; ++r) sj[j][r] = __shfl(sp[j][r], srcl[r], 64);
#pragma unroll
    for (int nt = 0; nt < 2; ++nt) {
      int tc = nt * 16 + fr;
#pragma unroll
      for (int r = 0; r < 4; ++r) {
        float pos = (fr <= crow + r) ? sj[nt][r] : sj[nt + 1][r];
        float e = EXP2(sc[nt][r] + pos);
        lsum[r] += e;
        Phw[crow + r][tc] = f2bf(e);
      }
    }
    s16x8 ah = *(const s16x8*)&Phw[fr][fc];
#pragma unroll
    for (int nt = 0; nt < 4; ++nt)
      Oacc[nt] = __builtin_amdgcn_mfma_f32_16x16x32_bf16(ah, vf[cur][nt],
                                                         Oacc[nt], 0, 0, 0);
  }
#pragma unroll
  for (int d = 1; d < 16; d <<= 1)
#pragma unroll
    for (int r = 0; r < 4; ++r) lsum[r] += __shfl_xor(lsum[r], d, 64);
  // epilogue: ctx in packed A-fragment layout for the out GEMM
#pragma unroll
  for (int nt = 0; nt < 4; ++nt)
#pragma unroll
    for (int r = 0; r < 4; ++r) {
      float o = Oacc[nt][r] / lsum[r];
      int row = b * 512 + s0w + crow + r;
      int col = h * 64 + nt * 16 + fr;
      ctxpk[pk(row, col)] = f2bf(o);
    }
}

// ---------------------------------------------------------------------------
extern "C" void kernel_launch(void* const* d_in, const int* in_sizes, int n_in,
                              void* d_out, int out_size, void* d_ws,
                              size_t ws_size, hipStream_t stream) {
  const float* x = (const float*)d_in[0];
  const float* pe = (const float*)d_in[1];
  const float* ln_g = (const float*)d_in[2];
  const float* ln_b = (const float*)d_in[3];
  const float* Wq = (const float*)d_in[4];
  const float* bq = (const float*)d_in[5];
  const float* Wk = (const float*)d_in[6];
  const float* bk = (const float*)d_in[7];
  const float* Wv = (const float*)d_in[8];
  const float* bv = (const float*)d_in[9];
  const float* Wp = (const float*)d_in[10];
  const float* bp = (const float*)d_in[11];
  const float* cb = (const float*)d_in[12];
  const float* pb = (const float*)d_in[13];
  const float* Wo = (const float*)d_in[14];
  const float* bo = (const float*)d_in[15];
  float* out = (float*)d_out;

  char* ws = (char*)d_ws;
  size_t off = 0;
  auto alloc = [&](size_t bytes) -> char* {
    char* ptr = ws + off;
    off = (off + bytes + 255) & ~(size_t)255;
    return ptr;
  };
  // xn packed (8.4 MB) -> reused as ctx packed after proj_all completes
  unsigned short* xpk = (unsigned short*)alloc((size_t)8192 * 512 * 2);
  unsigned short* ctxpk = xpk;
  unsigned short* pepk = (unsigned short*)alloc((size_t)16384 * 512 * 2);
  unsigned short* vt_hi = (unsigned short*)alloc((size_t)8192 * 512 * 2);
  unsigned short* wqk = (unsigned short*)alloc((size_t)1024 * 512 * 2);
  unsigned short* wpm = (unsigned short*)alloc((size_t)512 * 512 * 2);
  unsigned short* wvm = (unsigned short*)alloc((size_t)512 * 512 * 2);
  unsigned short* wom = (unsigned short*)alloc((size_t)512 * 512 * 2);
  float* bqk = (float*)alloc(1024 * 4);
  unsigned short* qc = (unsigned short*)alloc((size_t)8192 * 512 * 2);
  unsigned short* qp = (unsigned short*)alloc((size_t)8192 * 512 * 2);
  unsigned short* kbuf = (unsigned short*)alloc((size_t)8192 * 512 * 2);
  unsigned short* pbuf = (unsigned short*)alloc((size_t)16384 * 512 * 2);

  if (ws_size < off) {
    fprintf(stderr, "kernel_launch: ws too small (need %zu, have %zu)\n", off,
            ws_size);
    return;
  }

  megaprep<<<6784, 256, 0, stream>>>(x, ln_g, ln_b, xpk, pe, pepk, Wq, Wk, Wp,
                                     Wv, Wo, bq, bk, wqk, wpm, wvm, wom, bqk);
  proj_all<<<1280, 256, 0, stream>>>(xpk, pepk, wqk, wpm, wvm, bqk, bp, bv,
                                     cb, pb, qc, qp, kbuf, pbuf, vt_hi);
  flash_attn<<<1024, 256, 0, stream>>>(qc, qp, kbuf, pbuf, vt_hi, ctxpk);
  out_gemm<<<256, 256, 0, stream>>>(ctxpk, wom, bo, out);
}

// Round 11
// 218.743 us; speedup vs baseline: 9.7887x; 9.7887x over previous
//
#include <hip/hip_runtime.h>
#include <cstdio>
#include <cstdint>

// ---------------------------------------------------------------------------
// Transformer-XL relative MHA, MI355X/gfx950.  B=16 T=512 D=512 H=8 hd=64.
// Round 11: fix R10's flash scratch-spill catastrophe. The prefetch buffers
// were indexed with a RUNTIME index (kf[cur][..]) -> compiler demoted all
// fragments to scratch (WRITE_SIZE 16->195MB, 2070us). Now: two statically
// named buffer sets (A/B) + 2x-unrolled step loop, all indices compile-time.
// GEMM-side prefetch (R10) kept — it worked (non-flash 178->70us).
// pack(r,k) = (r>>4)*8192 + (k>>5)*512 + ((k>>3)&3)*128 + (r&15)*8 + (k&7)
// Precision: plain bf16 everywhere (absmax pinned by logit path at 0.0078).
// ---------------------------------------------------------------------------

typedef short s16x8 __attribute__((ext_vector_type(8)));
typedef float f32x4 __attribute__((ext_vector_type(4)));
typedef unsigned short u16x4 __attribute__((ext_vector_type(4)));
typedef unsigned short u16x8 __attribute__((ext_vector_type(8)));

#define CSCALE 0.1803368801111204f  // log2(e)/8

#if __has_builtin(__builtin_amdgcn_exp2f)
#define EXP2(x) __builtin_amdgcn_exp2f(x)
#else
#define EXP2(x) exp2f(x)
#endif

__device__ __forceinline__ unsigned short f2bf(float f) {  // RNE
  unsigned int u = __builtin_bit_cast(unsigned int, f);
  unsigned int r = (u + 0x7FFFu + ((u >> 16) & 1u)) >> 16;
  return (unsigned short)r;
}
__device__ __forceinline__ float bf2f(unsigned short h) {
  unsigned int u = ((unsigned int)h) << 16;
  return __builtin_bit_cast(float, u);
}
// fragment-strip packing: strips of 16 rows x 512 k (8192 shorts)
__device__ __forceinline__ size_t pk(int row, int col) {
  return (size_t)(row >> 4) * 8192 + (col >> 5) * 512 + ((col >> 3) & 3) * 128 +
         (row & 15) * 8 + (col & 7);
}

// ---------------- fused prep (vectorized stores) ---------------------------
__global__ __launch_bounds__(256) void megaprep(
    const float* __restrict__ x, const float* __restrict__ g,
    const float* __restrict__ bb, unsigned short* __restrict__ xpk,
    const float* __restrict__ pe, unsigned short* __restrict__ pepk,
    const float* __restrict__ Wq, const float* __restrict__ Wk,
    const float* __restrict__ Wp, const float* __restrict__ Wv,
    const float* __restrict__ Wo, const float* __restrict__ bq,
    const float* __restrict__ bk, unsigned short* __restrict__ wqk,
    unsigned short* __restrict__ wpm, unsigned short* __restrict__ wvm,
    unsigned short* __restrict__ wom, float* __restrict__ bqk) {
  const int bid = blockIdx.x, tid = threadIdx.x;
  if (bid < 2048) {  // LN: row = bid*4 + wave
    const int wave = tid >> 6, lane = tid & 63;
    const int row = bid * 4 + wave;
    const int c0 = lane * 8;
    const float* xr = x + (size_t)row * 512 + c0;
    float4 v0 = *(const float4*)xr;
    float4 v1 = *(const float4*)(xr + 4);
    float vv[8] = {v0.x, v0.y, v0.z, v0.w, v1.x, v1.y, v1.z, v1.w};
    float s = 0.f, ss = 0.f;
#pragma unroll
    for (int j = 0; j < 8; ++j) { s += vv[j]; ss += vv[j] * vv[j]; }
#pragma unroll
    for (int d = 1; d < 64; d <<= 1) {
      s += __shfl_xor(s, d, 64);
      ss += __shfl_xor(ss, d, 64);
    }
    const float mu = s * (1.0f / 512.0f);
    const float var = ss * (1.0f / 512.0f) - mu * mu;
    const float rstd = rsqrtf(var + 1e-5f);
    u16x8 o;
#pragma unroll
    for (int j = 0; j < 8; ++j)
      o[j] = f2bf((vv[j] - mu) * rstd * g[c0 + j] + bb[c0 + j]);
    *(u16x8*)(xpk + pk(row, c0)) = o;
  } else if (bid < 6144) {  // pe: 8 elems/thread
    int gid = (bid - 2048) * 256 + tid;
    int e = gid * 8;  // over 16384*512
    int r = e >> 9, c = e & 511;
    int b = r >> 10, u = r & 1023;
    u16x8 o = {0, 0, 0, 0, 0, 0, 0, 0};
    if (u < 1023) {
      const float* src = pe + (size_t)(b * 1023 + u) * 512 + c;
      float4 v0 = *(const float4*)src;
      float4 v1 = *(const float4*)(src + 4);
      o[0] = f2bf(v0.x); o[1] = f2bf(v0.y); o[2] = f2bf(v0.z); o[3] = f2bf(v0.w);
      o[4] = f2bf(v1.x); o[5] = f2bf(v1.y); o[6] = f2bf(v1.z); o[7] = f2bf(v1.w);
    }
    *(u16x8*)(pepk + (size_t)b * 524288 + pk(u, c)) = o;
  } else {  // weights: 8 elems/thread
    int gid = (bid - 6144) * 256 + tid;
    int idx = gid * 8;  // over 5*262144
    int region = idx >> 18, off = idx & 262143;
    const float* src = (region == 0)   ? Wq
                       : (region == 1) ? Wk
                       : (region == 2) ? Wp
                       : (region == 3) ? Wv
                                       : Wo;
    float4 v0 = *(const float4*)(src + off);
    float4 v1 = *(const float4*)(src + off + 4);
    u16x8 o;
    o[0] = f2bf(v0.x); o[1] = f2bf(v0.y); o[2] = f2bf(v0.z); o[3] = f2bf(v0.w);
    o[4] = f2bf(v1.x); o[5] = f2bf(v1.y); o[6] = f2bf(v1.z); o[7] = f2bf(v1.w);
    int n = off >> 9, k = off & 511;
    unsigned short* dst;
    int nrow = n;
    if (region == 0) { dst = wqk; }
    else if (region == 1) { dst = wqk; nrow = n + 512; }
    else if (region == 2) { dst = wpm; }
    else if (region == 3) { dst = wvm; }
    else { dst = wom; }
    *(u16x8*)(dst + pk(nrow, k)) = o;
    if (idx < 1024) {
#pragma unroll
      for (int j = 0; j < 8; j++) {
        int ii = idx + j;
        bqk[ii] = (ii < 512) ? bq[ii] : bk[ii - 512];
      }
    }
  }
}

// ---------------- direct-load 64x64 GEMM core, prefetched ------------------
// Fully-unrolled k-loop: buffer indices are compile-time (no scratch).
__device__ __forceinline__ void gemm64_direct(
    const unsigned short* __restrict__ Apk, const unsigned short* __restrict__ Bpk,
    int mstrip0, int nstrip0, int lane, f32x4 acc[4][4]) {
  const unsigned short* ab = Apk + (size_t)mstrip0 * 8192 + lane * 8;
  const unsigned short* bb = Bpk + (size_t)nstrip0 * 8192 + lane * 8;
  s16x8 af[2][4], bf[2][4];
#pragma unroll
  for (int mt = 0; mt < 4; ++mt) af[0][mt] = *(const s16x8*)(ab + mt * 8192);
#pragma unroll
  for (int nt = 0; nt < 4; ++nt) bf[0][nt] = *(const s16x8*)(bb + nt * 8192);
#pragma unroll
  for (int kc = 0; kc < 16; ++kc) {
    const int cur = kc & 1, nxt = cur ^ 1;
    if (kc < 15) {
#pragma unroll
      for (int mt = 0; mt < 4; ++mt)
        af[nxt][mt] = *(const s16x8*)(ab + (size_t)mt * 8192 + (kc + 1) * 512);
#pragma unroll
      for (int nt = 0; nt < 4; ++nt)
        bf[nxt][nt] = *(const s16x8*)(bb + (size_t)nt * 8192 + (kc + 1) * 512);
    }
#pragma unroll
    for (int mt = 0; mt < 4; ++mt)
#pragma unroll
      for (int nt = 0; nt < 4; ++nt)
        acc[mt][nt] = __builtin_amdgcn_mfma_f32_16x16x32_bf16(
            af[cur][mt], bf[cur][nt], acc[mt][nt], 0, 0, 0);
  }
}

// merged projections: wave-tiles — qk [0,2048), p [2048,4096), v [4096,5120)
__global__ __launch_bounds__(256) void proj_all(
    const unsigned short* __restrict__ xpk, const unsigned short* __restrict__ pepk,
    const unsigned short* __restrict__ wqk, const unsigned short* __restrict__ wpm,
    const unsigned short* __restrict__ wvm, const float* __restrict__ bqk,
    const float* __restrict__ bp, const float* __restrict__ bv,
    const float* __restrict__ cbv, const float* __restrict__ pbv,
    unsigned short* __restrict__ qc, unsigned short* __restrict__ qp,
    unsigned short* __restrict__ kb, unsigned short* __restrict__ pbuf,
    unsigned short* __restrict__ vth) {
  const int tid = threadIdx.x, lane = tid & 63, wave = tid >> 6;
  const int w = blockIdx.x * 4 + wave;
  const int fr = lane & 15, hi2 = lane >> 4;
  f32x4 fz = {0.f, 0.f, 0.f, 0.f};
  f32x4 acc[4][4];
#pragma unroll
  for (int i = 0; i < 4; i++)
#pragma unroll
    for (int j = 0; j < 4; j++) acc[i][j] = fz;

  if (w < 2048) {  // qk: 128 m-tiles x 16 n-tiles
    int m_t = w >> 4, n_t = w & 15;
    gemm64_direct(xpk, wqk, m_t * 4, n_t * 4, lane, acc);
    int m0 = m_t * 64, n0 = n_t * 64;
#pragma unroll
    for (int nt = 0; nt < 4; ++nt) {
      int col = n0 + nt * 16 + fr;
      float bval = bqk[col];
#pragma unroll
      for (int mt = 0; mt < 4; ++mt) {
        int row = m0 + mt * 16 + hi2 * 4;
        int b = row >> 9, s15 = row & 15, s16i = (row & 511) >> 4;
        if (col < 512) {
          int h = col >> 6, cc = col & 63;
          size_t idx = ((size_t)(b * 8 + h) * 32 + s16i) * 1024 +
                       (cc >> 5) * 512 + ((cc & 31) >> 3) * 128 + (cc & 7);
          float cbc = cbv[col], pbc = pbv[col];
#pragma unroll
          for (int r = 0; r < 4; ++r) {
            float val = acc[mt][nt][r] + bval;
            qc[idx + (s15 + r) * 8] = f2bf((val + cbc) * CSCALE);
            qp[idx + (s15 + r) * 8] = f2bf((val + pbc) * CSCALE);
          }
        } else {
          int c2 = col - 512, h = c2 >> 6, cc = c2 & 63;
          size_t idx = ((size_t)(b * 8 + h) * 32 + s16i) * 1024 +
                       (cc >> 5) * 512 + ((cc & 31) >> 3) * 128 + (cc & 7);
#pragma unroll
          for (int r = 0; r < 4; ++r)
            kb[idx + (s15 + r) * 8] = f2bf(acc[mt][nt][r] + bval);
        }
      }
    }
  } else if (w < 4096) {  // p: 256 m-tiles x 8 n-tiles (per-b packed A)
    int w2 = w - 2048;
    int m_t = w2 >> 3, n_t = w2 & 7;
    int bb_ = m_t >> 4;
    gemm64_direct(pepk + (size_t)bb_ * 524288, wpm, (m_t & 15) * 4, n_t * 4,
                  lane, acc);
    int m0e = m_t * 64, n0 = n_t * 64;
    int b = m0e >> 10, u0 = m0e & 1023;
#pragma unroll
    for (int nt = 0; nt < 4; ++nt) {
      int col = n0 + nt * 16 + fr;
      float bval = bp[col];
      int h = col >> 6, cc = col & 63;
      size_t cbase = (size_t)(b * 8 + h) * 64 * 1024 + (cc >> 5) * 512 +
                     ((cc & 31) >> 3) * 128 + (cc & 7);
#pragma unroll
      for (int mt = 0; mt < 4; ++mt) {
        int ub = u0 + mt * 16 + hi2 * 4;
#pragma unroll
        for (int r = 0; r < 4; ++r) {
          int u = ub + r;
          float val = (u >= 1023) ? 0.f : (acc[mt][nt][r] + bval);
          pbuf[cbase + (size_t)(u >> 4) * 1024 + (u & 15) * 8] = f2bf(val);
        }
      }
    }
  } else {  // v: 128 m-tiles x 8 n-tiles -> vT packed
    int w3 = w - 4096;
    int m_t = w3 >> 3, n_t = w3 & 7;
    gemm64_direct(xpk, wvm, m_t * 4, n_t * 4, lane, acc);
    int m0 = m_t * 64, n0 = n_t * 64;
#pragma unroll
    for (int nt = 0; nt < 4; ++nt) {
      int col = n0 + nt * 16 + fr;
      float bval = bv[col];
      int h = col >> 6, d = col & 63;
#pragma unroll
      for (int mt = 0; mt < 4; ++mt) {
        int rowb = m0 + mt * 16 + hi2 * 4;
        int b = rowb >> 9, t = rowb & 511;
        size_t idx = ((size_t)((b * 8 + h) * 4 + (d >> 4)) * 16 + (t >> 5)) * 512 +
                     ((t & 31) >> 3) * 128 + (d & 15) * 8 + (t & 7);
        u16x4 hv;
#pragma unroll
        for (int r = 0; r < 4; ++r) hv[r] = f2bf(acc[mt][nt][r] + bval);
        *(u16x4*)(vth + idx) = hv;
      }
    }
  }
}

__global__ __launch_bounds__(256) void out_gemm(
    const unsigned short* __restrict__ ctxpk, const unsigned short* __restrict__ wom,
    const float* __restrict__ bo, float* __restrict__ out) {
  const int tid = threadIdx.x, lane = tid & 63, wave = tid >> 6;
  const int w = blockIdx.x * 4 + wave;  // 1024 waves: 128 m x 8 n
  const int fr = lane & 15, hi2 = lane >> 4;
  int m_t = w >> 3, n_t = w & 7;
  f32x4 fz = {0.f, 0.f, 0.f, 0.f};
  f32x4 acc[4][4];
#pragma unroll
  for (int i = 0; i < 4; i++)
#pragma unroll
    for (int j = 0; j < 4; j++) acc[i][j] = fz;
  gemm64_direct(ctxpk, wom, m_t * 4, n_t * 4, lane, acc);
  int m0 = m_t * 64, n0 = n_t * 64;
#pragma unroll
  for (int nt = 0; nt < 4; ++nt) {
    int col = n0 + nt * 16 + fr;
    float bval = bo[col];
#pragma unroll
    for (int mt = 0; mt < 4; ++mt) {
      int row = m0 + mt * 16 + hi2 * 4;
#pragma unroll
      for (int r = 0; r < 4; ++r)
        out[(size_t)(row + r) * 512 + col] = acc[mt][nt][r] + bval;
    }
  }
}

// ---------------- barrier-free flash attention, static-buffer pipeline -----
// grid 1024; id%128=(b,h). Wave owns 16 q-rows. Fixed-max softmax. Two
// statically-named fragment buffer sets; step loop unrolled 2x so every
// buffer reference is compile-time (NO dynamic array indexing -> no scratch).
__global__ __launch_bounds__(256) void flash_attn(
    const unsigned short* __restrict__ qc, const unsigned short* __restrict__ qp,
    const unsigned short* __restrict__ kb, const unsigned short* __restrict__ pm,
    const unsigned short* __restrict__ vth, unsigned short* __restrict__ ctxpk) {
  const int id = blockIdx.x;
  const int bh = id & 127, b = bh >> 3, h = bh & 7;
  const int s_blk = id >> 7;
  const int tid = threadIdx.x, wave = tid >> 6, lane = tid & 63;
  const int fr = lane & 15, hi2 = lane >> 4, fc = hi2 * 8;
  const int s0w = s_blk * 64 + wave * 16;
  const int crow = hi2 * 4;

  __shared__ __align__(16) unsigned short Ph_s[4][16][40];
  unsigned short(*Phw)[40] = Ph_s[wave];

  int srcl[4];
#pragma unroll
  for (int r = 0; r < 4; ++r) srcl[r] = (hi2 << 4) | ((fr - (crow + r) - 1) & 15);

  const size_t qtb = ((size_t)(b * 8 + h) * 32 + (s0w >> 4)) * 1024 + lane * 8;
  s16x8 aqc0 = *(const s16x8*)(qc + qtb);
  s16x8 aqc1 = *(const s16x8*)(qc + qtb + 512);
  s16x8 aqp0 = *(const s16x8*)(qp + qtb);
  s16x8 aqp1 = *(const s16x8*)(qp + qtb + 512);

  const unsigned short* kpk = kb + (size_t)(b * 8 + h) * 32 * 1024 + lane * 8;
  const unsigned short* ppk = pm + (size_t)(b * 8 + h) * 64 * 1024 + lane * 8;
  const unsigned short* vhk = vth + (size_t)(b * 8 + h) * 64 * 512 + lane * 8;

  f32x4 fz = {0.f, 0.f, 0.f, 0.f};
  f32x4 Oacc[4] = {fz, fz, fz, fz};
  float lsum[4] = {0.f, 0.f, 0.f, 0.f};

  s16x8 kfA[4], pfA[6], vfA[4], kfB[4], pfB[6], vfB[4];

  // load fragments for `step` into the given (statically-named) buffers
#define LOADF(step, kf, pf, vf)                                              \
  {                                                                          \
    const int t0_ = (step) * 32;                                             \
    const int u0w_ = t0_ - s0w + 496;                                        \
    const int kt_ = t0_ >> 4, ut_ = u0w_ >> 4, vt_ = t0_ >> 5;               \
    _Pragma("unroll") for (int nt = 0; nt < 2; ++nt) {                       \
      const unsigned short* kr = kpk + (size_t)(kt_ + nt) * 1024;            \
      kf[2 * nt] = *(const s16x8*)kr;                                        \
      kf[2 * nt + 1] = *(const s16x8*)(kr + 512);                            \
    }                                                                        \
    _Pragma("unroll") for (int nt = 0; nt < 3; ++nt) {                       \
      const unsigned short* pr = ppk + (size_t)(ut_ + nt) * 1024;            \
      pf[2 * nt] = *(const s16x8*)pr;                                        \
      pf[2 * nt + 1] = *(const s16x8*)(pr + 512);                            \
    }                                                                        \
    _Pragma("unroll") for (int nt = 0; nt < 4; ++nt)                         \
        vf[nt] = *(const s16x8*)(vhk + (size_t)(nt * 16 + vt_) * 512);       \
  }

  // one attention step using the given buffers
#define STEPF(kf, pf, vf)                                                    \
  {                                                                          \
    f32x4 sc[2] = {fz, fz};                                                  \
    _Pragma("unroll") for (int nt = 0; nt < 2; ++nt) {                       \
      sc[nt] = __builtin_amdgcn_mfma_f32_16x16x32_bf16(aqc0, kf[2 * nt],     \
                                                       sc[nt], 0, 0, 0);     \
      sc[nt] = __builtin_amdgcn_mfma_f32_16x16x32_bf16(aqc1, kf[2 * nt + 1], \
                                                       sc[nt], 0, 0, 0);     \
    }                                                                        \
    f32x4 sp[3];                                                             \
    _Pragma("unroll") for (int nt = 0; nt < 3; ++nt) {                       \
      f32x4 t = fz;                                                          \
      t = __builtin_amdgcn_mfma_f32_16x16x32_bf16(aqp0, pf[2 * nt], t, 0, 0, 0); \
      t = __builtin_amdgcn_mfma_f32_16x16x32_bf16(aqp1, pf[2 * nt + 1], t, 0, 0, 0); \
      sp[nt] = t;                                                            \
    }                                                                        \
    float sj[3][4];                                                          \
    _Pragma("unroll") for (int j = 0; j < 3; ++j)                            \
        _Pragma("unroll") for (int r = 0; r < 4; ++r)                        \
        sj[j][r] = __shfl(sp[j][r], srcl[r], 64);                            \
    _Pragma("unroll") for (int nt = 0; nt < 2; ++nt) {                       \
      int tc = nt * 16 + fr;                                                 \
      _Pragma("unroll") for (int r = 0; r < 4; ++r) {                        \
        float pos = (fr <= crow + r) ? sj[nt][r] : sj[nt + 1][r];            \
        float e = EXP2(sc[nt][r] + pos);                                     \
        lsum[r] += e;                                                        \
        Phw[crow + r][tc] = f2bf(e);                                         \
      }                                                                      \
    }                                                                        \
    s16x8 ah = *(const s16x8*)&Phw[fr][fc];                                  \
    _Pragma("unroll") for (int nt = 0; nt < 4; ++nt)                         \
        Oacc[nt] = __builtin_amdgcn_mfma_f32_16x16x32_bf16(ah, vf[nt],       \
                                                           Oacc[nt], 0, 0, 0); \
  }

  LOADF(0, kfA, pfA, vfA);
  for (int s2 = 0; s2 < 8; ++s2) {
    LOADF(2 * s2 + 1, kfB, pfB, vfB);
    STEPF(kfA, pfA, vfA);
    if (s2 < 7) LOADF(2 * s2 + 2, kfA, pfA, vfA);
    STEPF(kfB, pfB, vfB);
  }
#undef LOADF
#undef STEPF

#pragma unroll
  for (int d = 1; d < 16; d <<= 1)
#pragma unroll
    for (int r = 0; r < 4; ++r) lsum[r] += __shfl_xor(lsum[r], d, 64);
  // epilogue: ctx in packed A-fragment layout for the out GEMM
#pragma unroll
  for (int nt = 0; nt < 4; ++nt)
#pragma unroll
    for (int r = 0; r < 4; ++r) {
      float o = Oacc[nt][r] / lsum[r];
      int row = b * 512 + s0w + crow + r;
      int col = h * 64 + nt * 16 + fr;
      ctxpk[pk(row, col)] = f2bf(o);
    }
}

// ---------------------------------------------------------------------------
extern "C" void kernel_launch(void* const* d_in, const int* in_sizes, int n_in,
                              void* d_out, int out_size, void* d_ws,
                              size_t ws_size, hipStream_t stream) {
  const float* x = (const float*)d_in[0];
  const float* pe = (const float*)d_in[1];
  const float* ln_g = (const float*)d_in[2];
  const float* ln_b = (const float*)d_in[3];
  const float* Wq = (const float*)d_in[4];
  const float* bq = (const float*)d_in[5];
  const float* Wk = (const float*)d_in[6];
  const float* bk = (const float*)d_in[7];
  const float* Wv = (const float*)d_in[8];
  const float* bv = (const float*)d_in[9];
  const float* Wp = (const float*)d_in[10];
  const float* bp = (const float*)d_in[11];
  const float* cb = (const float*)d_in[12];
  const float* pb = (const float*)d_in[13];
  const float* Wo = (const float*)d_in[14];
  const float* bo = (const float*)d_in[15];
  float* out = (float*)d_out;

  char* ws = (char*)d_ws;
  size_t off = 0;
  auto alloc = [&](size_t bytes) -> char* {
    char* ptr = ws + off;
    off = (off + bytes + 255) & ~(size_t)255;
    return ptr;
  };
  // xn packed (8.4 MB) -> reused as ctx packed after proj_all completes
  unsigned short* xpk = (unsigned short*)alloc((size_t)8192 * 512 * 2);
  unsigned short* ctxpk = xpk;
  unsigned short* pepk = (unsigned short*)alloc((size_t)16384 * 512 * 2);
  unsigned short* vt_hi = (unsigned short*)alloc((size_t)8192 * 512 * 2);
  unsigned short* wqk = (unsigned short*)alloc((size_t)1024 * 512 * 2);
  unsigned short* wpm = (unsigned short*)alloc((size_t)512 * 512 * 2);
  unsigned short* wvm = (unsigned short*)alloc((size_t)512 * 512 * 2);
  unsigned short* wom = (unsigned short*)alloc((size_t)512 * 512 * 2);
  float* bqk = (float*)alloc(1024 * 4);
  unsigned short* qc = (unsigned short*)alloc((size_t)8192 * 512 * 2);
  unsigned short* qp = (unsigned short*)alloc((size_t)8192 * 512 * 2);
  unsigned short* kbuf = (unsigned short*)alloc((size_t)8192 * 512 * 2);
  unsigned short* pbuf = (unsigned short*)alloc((size_t)16384 * 512 * 2);

  if (ws_size < off) {
    fprintf(stderr, "kernel_launch: ws too small (need %zu, have %zu)\n", off,
            ws_size);
    return;
  }

  megaprep<<<6784, 256, 0, stream>>>(x, ln_g, ln_b, xpk, pe, pepk, Wq, Wk, Wp,
                                     Wv, Wo, bq, bk, wqk, wpm, wvm, wom, bqk);
  proj_all<<<1280, 256, 0, stream>>>(xpk, pepk, wqk, wpm, wvm, bqk, bp, bv,
                                     cb, pb, qc, qp, kbuf, pbuf, vt_hi);
  flash_attn<<<1024, 256, 0, stream>>>(qc, qp, kbuf, pbuf, vt_hi, ctxpk);
  out_gemm<<<256, 256, 0, stream>>>(ctxpk, wom, bo, out);
}